// Round 16
// baseline (179.566 us; speedup 1.0000x reference)
//
#include <hip/hip_runtime.h>

#define NSIG  65536
#define KAT   512
#define CDIM  64

__device__ __forceinline__ float bcastf(float v, int l) {
  return __int_as_float(__builtin_amdgcn_readlane(__float_as_int(v), l));
}
__device__ __forceinline__ unsigned umaxu(unsigned a, unsigned b) {
  return a > b ? a : b;
}
__device__ __forceinline__ unsigned dppmax(unsigned v, const int ctrl) {
  switch (ctrl) {
    case 0xB1:  return umaxu(v, (unsigned)__builtin_amdgcn_mov_dpp((int)v, 0xB1, 0xF, 0xF, true));
    case 0x4E:  return umaxu(v, (unsigned)__builtin_amdgcn_mov_dpp((int)v, 0x4E, 0xF, 0xF, true));
    case 0x124: return umaxu(v, (unsigned)__builtin_amdgcn_mov_dpp((int)v, 0x124, 0xF, 0xF, true));
    case 0x128: return umaxu(v, (unsigned)__builtin_amdgcn_mov_dpp((int)v, 0x128, 0xF, 0xF, true));
    case 0x142: return umaxu(v, (unsigned)__builtin_amdgcn_mov_dpp((int)v, 0x142, 0xF, 0xF, true));
    default:    return umaxu(v, (unsigned)__builtin_amdgcn_mov_dpp((int)v, 0x143, 0xF, 0xF, true));
  }
}

// G = D^T D  [512][512]; DT[k][c] = D[c][k]
__global__ void k_gram(const float* __restrict__ D, float* __restrict__ G,
                       float* __restrict__ DT) {
  int tid = blockIdx.x * 256 + threadIdx.x;      // 262144 total
  int i = tid >> 9, j = tid & 511;
  float acc = 0.f;
  #pragma unroll 8
  for (int c = 0; c < CDIM; ++c) acc = fmaf(D[c * KAT + i], D[c * KAT + j], acc);
  G[tid] = acc;
  if (tid < KAT * CDIM) {
    int k = tid >> 6, c = tid & 63;
    DT[tid] = D[c * KAT + k];
  }
}

// ST[n][b] = z_e[b][n%64][n/2048][(n/64)%32]   (signal-major staging)
__global__ void k_tr(const float* __restrict__ ze, float* __restrict__ st) {
  __shared__ float tile[64][33];
  int cz = blockIdx.x >> 5;
  int h  = blockIdx.x & 31;
  int t  = threadIdx.x;
  #pragma unroll
  for (int q = 0; q < 8; ++q) {
    int idx = q * 256 + t;
    int b = idx >> 5, w = idx & 31;
    tile[b][w] = ze[b * 65536 + cz * 1024 + h * 32 + w];
  }
  __syncthreads();
  #pragma unroll
  for (int q = 0; q < 8; ++q) {
    int idx = q * 256 + t;
    int w = idx >> 6, b = idx & 63;
    st[(h * 2048 + w * 64 + cz) * 64 + b] = tile[b][w];
  }
}

// ---- all-scalar helpers ----
#define DECL8Z(p) float p##0=0.f,p##1=0.f,p##2=0.f,p##3=0.f,p##4=0.f,p##5=0.f,p##6=0.f,p##7=0.f
#define FMA8(p, sc)                                         \
  p##0 = fmaf(d0.x, sc, p##0); p##1 = fmaf(d0.y, sc, p##1); \
  p##2 = fmaf(d0.z, sc, p##2); p##3 = fmaf(d0.w, sc, p##3); \
  p##4 = fmaf(d1.x, sc, p##4); p##5 = fmaf(d1.y, sc, p##5); \
  p##6 = fmaf(d1.z, sc, p##6); p##7 = fmaf(d1.w, sc, p##7)
#define SEL8(e, p)                                          \
  e = p##0;                                                 \
  e = (jj == 1) ? p##1 : e; e = (jj == 2) ? p##2 : e;       \
  e = (jj == 3) ? p##3 : e; e = (jj == 4) ? p##4 : e;       \
  e = (jj == 5) ? p##5 : e; e = (jj == 6) ? p##6 : e;       \
  e = (jj == 7) ? p##7 : e
#define ORTHO8(Qp, w)                                           \
  qn0 = fmaf(-(w), Qp##0, qn0); qn1 = fmaf(-(w), Qp##1, qn1);   \
  qn2 = fmaf(-(w), Qp##2, qn2); qn3 = fmaf(-(w), Qp##3, qn3);   \
  qn4 = fmaf(-(w), Qp##4, qn4); qn5 = fmaf(-(w), Qp##5, qn5);   \
  qn6 = fmaf(-(w), Qp##6, qn6); qn7 = fmaf(-(w), Qp##7, qn7)
#define SETQ8(Qp)                                               \
  Qp##0 = qn0; Qp##1 = qn1; Qp##2 = qn2; Qp##3 = qn3;           \
  Qp##4 = qn4; Qp##5 = qn5; Qp##6 = qn6; Qp##7 = qn7

// One full OMP solve for one signal; cr in 8 scalar refs. ALL FOUR Q columns
// live in registers; w_u = Q_u[khat] extracts are register SEL8 + readlane
// (~30 cy) instead of LDS uniform loads (~120 cy) — no LDS in this kernel.
__device__ __forceinline__ float omp_one(
    float& c0, float& c1, float& c2, float& c3,
    float& c4, float& c5, float& c6, float& c7,
    const float* __restrict__ G, const float* __restrict__ DT,
    float* __restrict__ coeffs,
    int n, int lane, float zv) {
  int omega = 0xFF;
  int I0 = 0, I1 = 0, I2 = 0, I3 = 0, I4 = 0;
  float L10 = 0, L20 = 0, L21 = 0;
  float L30 = 0, L31 = 0, L32 = 0;
  float L40 = 0, L41 = 0, L42 = 0, L43 = 0;
  float d1v = 1.f, d2v = 1.f, d3v = 1.f, d4v = 1.f;
  float y0v = 0, y1v = 0, y2v = 0, y3v = 0, y4v = 0;
  DECL8Z(Qa); DECL8Z(Qb); DECL8Z(Qc); DECL8Z(Qd);   // all 4 cols in regs

  #pragma unroll
  for (int it = 0; it < 5; ++it) {
    // ---- argmax of |cr|*omega: pure-DPP reduce, first-index tie-break ----
    unsigned ab0 = (omega & 1)        ? (__float_as_uint(c0) & 0x7FFFFFFFu) : 0u;
    unsigned ab1 = ((omega >> 1) & 1) ? (__float_as_uint(c1) & 0x7FFFFFFFu) : 0u;
    unsigned ab2 = ((omega >> 2) & 1) ? (__float_as_uint(c2) & 0x7FFFFFFFu) : 0u;
    unsigned ab3 = ((omega >> 3) & 1) ? (__float_as_uint(c3) & 0x7FFFFFFFu) : 0u;
    unsigned ab4 = ((omega >> 4) & 1) ? (__float_as_uint(c4) & 0x7FFFFFFFu) : 0u;
    unsigned ab5 = ((omega >> 5) & 1) ? (__float_as_uint(c5) & 0x7FFFFFFFu) : 0u;
    unsigned ab6 = ((omega >> 6) & 1) ? (__float_as_uint(c6) & 0x7FFFFFFFu) : 0u;
    unsigned ab7 = ((omega >> 7) & 1) ? (__float_as_uint(c7) & 0x7FFFFFFFu) : 0u;
    unsigned la = umaxu(umaxu(umaxu(ab0, ab1), umaxu(ab2, ab3)),
                        umaxu(umaxu(ab4, ab5), umaxu(ab6, ab7)));
    unsigned rmax = la;
    rmax = dppmax(rmax, 0xB1);    // quad xor1
    rmax = dppmax(rmax, 0x4E);    // quad xor2
    rmax = dppmax(rmax, 0x124);   // row_ror:4
    rmax = dppmax(rmax, 0x128);   // row_ror:8  -> per-row max
    rmax = dppmax(rmax, 0x142);   // row_bcast15
    rmax = dppmax(rmax, 0x143);   // row_bcast31 -> lane 63 has global max
    unsigned gmu = (unsigned)__builtin_amdgcn_readlane((int)rmax, 63);
    unsigned long long ball = __ballot(la == gmu);
    const int sl = __ffsll((long long)ball) - 1;   // lowest winning lane
    int jb = 7;
    jb = (ab6 == gmu) ? 6 : jb;
    jb = (ab5 == gmu) ? 5 : jb;
    jb = (ab4 == gmu) ? 4 : jb;
    jb = (ab3 == gmu) ? 3 : jb;
    jb = (ab2 == gmu) ? 2 : jb;
    jb = (ab1 == gmu) ? 1 : jb;
    jb = (ab0 == gmu) ? 0 : jb;
    const int jj = __builtin_amdgcn_readlane(jb, sl) & 7;
    const int khat = (sl << 3) | jj;
    if (lane == sl) omega &= ~(1 << jj);

    // new G row load (issued early; consumed after scalar chain)
    float4 na = {0, 0, 0, 0}, nbv = {0, 0, 0, 0};
    if (it < 4) {
      na  = *reinterpret_cast<const float4*>(G + khat * KAT + 8 * lane);
      nbv = *reinterpret_cast<const float4*>(G + khat * KAT + 8 * lane + 4);
    }

    // ---- register extracts: w_u = Q_u[khat], crv = cr[khat] ----
    float w0 = 0.f, w1 = 0.f, w2 = 0.f, w3 = 0.f;
    if (it > 0) { float e; SEL8(e, Qa); w0 = bcastf(e, sl); }
    if (it > 1) { float e; SEL8(e, Qb); w1 = bcastf(e, sl); }
    if (it > 2) { float e; SEL8(e, Qc); w2 = bcastf(e, sl); }
    if (it > 3) { float e; SEL8(e, Qd); w3 = bcastf(e, sl); }
    float crv;
    { float e; SEL8(e, c); crv = bcastf(e, sl); }

    // ---- scalar chain: dn = rsqrt(1-||w||^2); y_it = crv*dn ----
    float s2 = 1.f - w0 * w0 - w1 * w1 - w2 * w2 - w3 * w3;
    float dn = __builtin_amdgcn_rsqf(s2);          // rsq(1.0)==1.0 at it==0
    float yn = crv * dn;
    if (it == 0) { I0 = khat; y0v = yn; }
    if (it == 1) { I1 = khat; y1v = yn; L10 = w0; d1v = dn; }
    if (it == 2) { I2 = khat; y2v = yn; L20 = w0; L21 = w1; d2v = dn; }
    if (it == 3) { I3 = khat; y3v = yn; L30 = w0; L31 = w1; L32 = w2; d3v = dn; }
    if (it == 4) { I4 = khat; y4v = yn; L40 = w0; L41 = w1; L42 = w2; L43 = w3; d4v = dn; }

    // ---- orthogonalize new column (pure-register FMA); rank-1 update ----
    if (it < 4) {
      float qn0 = na.x,  qn1 = na.y,  qn2 = na.z,  qn3 = na.w;
      float qn4 = nbv.x, qn5 = nbv.y, qn6 = nbv.z, qn7 = nbv.w;
      if (it > 0) { ORTHO8(Qa, w0); }
      if (it > 1) { ORTHO8(Qb, w1); }
      if (it > 2) { ORTHO8(Qc, w2); }
      qn0 *= dn; qn1 *= dn; qn2 *= dn; qn3 *= dn;
      qn4 *= dn; qn5 *= dn; qn6 *= dn; qn7 *= dn;
      if (it == 0) { SETQ8(Qa); }
      if (it == 1) { SETQ8(Qb); }
      if (it == 2) { SETQ8(Qc); }
      if (it == 3) { SETQ8(Qd); }
      c0 = fmaf(-yn, qn0, c0); c1 = fmaf(-yn, qn1, c1);
      c2 = fmaf(-yn, qn2, c2); c3 = fmaf(-yn, qn3, c3);
      c4 = fmaf(-yn, qn4, c4); c5 = fmaf(-yn, qn5, c5);
      c6 = fmaf(-yn, qn6, c6); c7 = fmaf(-yn, qn7, c7);
    }
  } // it

  // ---- back-substitution (once) + epilogue ----
  float x4 = y4v * d4v;
  float x3 = (y3v - L43 * x4) * d3v;
  float x2 = (y2v - L32 * x3 - L42 * x4) * d2v;
  float x1 = (y1v - L21 * x2 - L31 * x3 - L41 * x4) * d1v;
  float x0 =  y0v - L10 * x1 - L20 * x2 - L30 * x3 - L40 * x4;

  if (lane < 5) {
    int It = I0; float xt = x0;
    if (lane == 1) { It = I1; xt = x1; }
    if (lane == 2) { It = I2; xt = x2; }
    if (lane == 3) { It = I3; xt = x3; }
    if (lane == 4) { It = I4; xt = x4; }
    coeffs[(long)It * NSIG + n] = xt;
  }
  float rec = x0 * DT[I0 * 64 + lane];
  rec = fmaf(x1, DT[I1 * 64 + lane], rec);
  rec = fmaf(x2, DT[I2 * 64 + lane], rec);
  rec = fmaf(x3, DT[I3 * 64 + lane], rec);
  rec = fmaf(x4, DT[I4 * 64 + lane], rec);
  return rec - zv;                       // d = z_dl - z (per-lane component)
}

// one wave per block; no LDS at all
__global__ __launch_bounds__(64) void k_omp(
    const float* __restrict__ D, const float* __restrict__ G,
    const float* __restrict__ DT, const float* __restrict__ ST,
    float* __restrict__ out0, float* __restrict__ lossp,
    float* __restrict__ coeffs) {
  const int lane = threadIdx.x;
  const int wid  = blockIdx.x;                              // 0..8191
  // strided signal mapping: n_j = cc + 512*w3 + 64*j (j=0..7): each lane's
  // 8 out0 values are consecutive floats -> coalesced stores, no write amp.
  const int cc = wid >> 7;          // 0..63  (= n & 63)
  const int w3 = wid & 127;
  const int nbase = cc + 512 * w3;
  const float* Dp = D + 8 * lane;
  float lossacc = 0.f;

  // ONE group of 8 signals: D streamed from L2 exactly once per wave.
  const int n0 = nbase;             const int n1 = nbase + 64;
  const int n2 = nbase + 128;       const int n3 = nbase + 192;
  const int n4 = nbase + 256;       const int n5 = nbase + 320;
  const int n6 = nbase + 384;       const int n7 = nbase + 448;
  float svA = ST[n0 * 64 + lane];
  float svB = ST[n1 * 64 + lane];
  float svC = ST[n2 * 64 + lane];
  float svD = ST[n3 * 64 + lane];
  float svE = ST[n4 * 64 + lane];
  float svF = ST[n5 * 64 + lane];
  float svG = ST[n6 * 64 + lane];
  float svH = ST[n7 * 64 + lane];

  DECL8Z(cA); DECL8Z(cB); DECL8Z(cC); DECL8Z(cD);
  DECL8Z(cE); DECL8Z(cF); DECL8Z(cG); DECL8Z(cH);

  #pragma unroll 2
  for (int r = 0; r < 64; ++r) {
    const float4 d0 = *reinterpret_cast<const float4*>(Dp + r * KAT);
    const float4 d1 = *reinterpret_cast<const float4*>(Dp + r * KAT + 4);
    const float sA = bcastf(svA, r);
    const float sB = bcastf(svB, r);
    const float sC = bcastf(svC, r);
    const float sD = bcastf(svD, r);
    const float sE = bcastf(svE, r);
    const float sF = bcastf(svF, r);
    const float sG = bcastf(svG, r);
    const float sH = bcastf(svH, r);
    FMA8(cA, sA); FMA8(cB, sB); FMA8(cC, sC); FMA8(cD, sD);
    FMA8(cE, sE); FMA8(cF, sF); FMA8(cG, sG); FMA8(cH, sH);
  }

  float dA = omp_one(cA0, cA1, cA2, cA3, cA4, cA5, cA6, cA7,
                     G, DT, coeffs, n0, lane, svA);
  lossacc = fmaf(dA, dA, lossacc);
  float dB = omp_one(cB0, cB1, cB2, cB3, cB4, cB5, cB6, cB7,
                     G, DT, coeffs, n1, lane, svB);
  lossacc = fmaf(dB, dB, lossacc);
  float dC = omp_one(cC0, cC1, cC2, cC3, cC4, cC5, cC6, cC7,
                     G, DT, coeffs, n2, lane, svC);
  lossacc = fmaf(dC, dC, lossacc);
  float dD = omp_one(cD0, cD1, cD2, cD3, cD4, cD5, cD6, cD7,
                     G, DT, coeffs, n3, lane, svD);
  lossacc = fmaf(dD, dD, lossacc);
  float dE = omp_one(cE0, cE1, cE2, cE3, cE4, cE5, cE6, cE7,
                     G, DT, coeffs, n4, lane, svE);
  lossacc = fmaf(dE, dE, lossacc);
  float dF = omp_one(cF0, cF1, cF2, cF3, cF4, cF5, cF6, cF7,
                     G, DT, coeffs, n5, lane, svF);
  lossacc = fmaf(dF, dF, lossacc);
  float dG = omp_one(cG0, cG1, cG2, cG3, cG4, cG5, cG6, cG7,
                     G, DT, coeffs, n6, lane, svG);
  lossacc = fmaf(dG, dG, lossacc);
  float dH = omp_one(cH0, cH1, cH2, cH3, cH4, cH5, cH6, cH7,
                     G, DT, coeffs, n7, lane, svH);
  lossacc = fmaf(dH, dH, lossacc);

  // out0: 8 consecutive floats per lane (32B-aligned), two dwordx4 stores
  const int obase = lane * 65536 + cc * 1024 + (w3 >> 2) * 32 + (w3 & 3) * 8;
  *reinterpret_cast<float4*>(out0 + obase) =
      make_float4(svA + dA, svB + dB, svC + dC, svD + dD);
  *reinterpret_cast<float4*>(out0 + obase + 4) =
      make_float4(svE + dE, svF + dF, svG + dG, svH + dH);

  #pragma unroll
  for (int off = 32; off > 0; off >>= 1) lossacc += __shfl_xor(lossacc, off);
  if (lane == 0) atomicAdd(lossp, lossacc * (1.25f / 4194304.f));
}

extern "C" void kernel_launch(void* const* d_in, const int* in_sizes, int n_in,
                              void* d_out, int out_size, void* d_ws, size_t ws_size,
                              hipStream_t stream) {
  const float* ze = (const float*)d_in[0];
  const float* D  = (const float*)d_in[1];
  float* out0 = (float*)d_out;
  float* lossp = out0 + 4194304;
  float* coeffs = out0 + 4194305;

  float* wsf = (float*)d_ws;
  float* G  = wsf;              // 262144 floats
  float* DT = wsf + 262144;     // 32768 floats
  float* ST = wsf + 294912;     // 4194304 floats

  // zero loss + coeffs (out0 is fully overwritten)
  (void)hipMemsetAsync((char*)d_out + 16777216ull, 0, 134217732ull, stream);

  hipLaunchKernelGGL(k_gram, dim3(1024), dim3(256), 0, stream, D, G, DT);
  hipLaunchKernelGGL(k_tr,   dim3(2048), dim3(256), 0, stream, ze, ST);
  hipLaunchKernelGGL(k_omp,  dim3(8192), dim3(64), 0, stream,
                     D, G, DT, ST, out0, lossp, coeffs);
}

// Round 17
// 173.792 us; speedup vs baseline: 1.0332x; 1.0332x over previous
//
#include <hip/hip_runtime.h>

#define NSIG  65536
#define KAT   512
#define CDIM  64

typedef float f32x4 __attribute__((ext_vector_type(4)));

__device__ __forceinline__ f32x4 splat4(float x) { return (f32x4){x, x, x, x}; }
__device__ __forceinline__ float bcastf(float v, int l) {
  return __int_as_float(__builtin_amdgcn_readlane(__float_as_int(v), l));
}
__device__ __forceinline__ unsigned umaxu(unsigned a, unsigned b) {
  return a > b ? a : b;
}
__device__ __forceinline__ unsigned dppmax(unsigned v, const int ctrl) {
  switch (ctrl) {
    case 0xB1:  return umaxu(v, (unsigned)__builtin_amdgcn_mov_dpp((int)v, 0xB1, 0xF, 0xF, true));
    case 0x4E:  return umaxu(v, (unsigned)__builtin_amdgcn_mov_dpp((int)v, 0x4E, 0xF, 0xF, true));
    case 0x124: return umaxu(v, (unsigned)__builtin_amdgcn_mov_dpp((int)v, 0x124, 0xF, 0xF, true));
    case 0x128: return umaxu(v, (unsigned)__builtin_amdgcn_mov_dpp((int)v, 0x128, 0xF, 0xF, true));
    case 0x142: return umaxu(v, (unsigned)__builtin_amdgcn_mov_dpp((int)v, 0x142, 0xF, 0xF, true));
    default:    return umaxu(v, (unsigned)__builtin_amdgcn_mov_dpp((int)v, 0x143, 0xF, 0xF, true));
  }
}

// G = D^T D  [512][512]; DT[k][c] = D[c][k]
__global__ void k_gram(const float* __restrict__ D, float* __restrict__ G,
                       float* __restrict__ DT) {
  int tid = blockIdx.x * 256 + threadIdx.x;      // 262144 total
  int i = tid >> 9, j = tid & 511;
  float acc = 0.f;
  #pragma unroll 8
  for (int c = 0; c < CDIM; ++c) acc = fmaf(D[c * KAT + i], D[c * KAT + j], acc);
  G[tid] = acc;
  if (tid < KAT * CDIM) {
    int k = tid >> 6, c = tid & 63;
    DT[tid] = D[c * KAT + k];
  }
}

// ST[n][b] = z_e[b][n%64][n/2048][(n/64)%32]   (signal-major staging)
__global__ void k_tr(const float* __restrict__ ze, float* __restrict__ st) {
  __shared__ float tile[64][33];
  int cz = blockIdx.x >> 5;
  int h  = blockIdx.x & 31;
  int t  = threadIdx.x;
  #pragma unroll
  for (int q = 0; q < 8; ++q) {
    int idx = q * 256 + t;
    int b = idx >> 5, w = idx & 31;
    tile[b][w] = ze[b * 65536 + cz * 1024 + h * 32 + w];
  }
  __syncthreads();
  #pragma unroll
  for (int q = 0; q < 8; ++q) {
    int idx = q * 256 + t;
    int w = idx >> 6, b = idx & 63;
    st[(h * 2048 + w * 64 + cz) * 64 + b] = tile[b][w];
  }
}

// ---- vector helpers (f32x4 pairs; compiler lowers to v_pk_fma_f32) ----
#define DECLV(p) f32x4 p##03 = {0,0,0,0}, p##47 = {0,0,0,0}
#define FMA8V(p, sc)                                                   \
  { f32x4 s4 = splat4(sc);                                             \
    p##03 = __builtin_elementwise_fma(d03, s4, p##03);                 \
    p##47 = __builtin_elementwise_fma(d47, s4, p##47); }
#define SEL8V(e, v03, v47)                                             \
  e = v03[0];                                                          \
  e = (jj == 1) ? v03[1] : e; e = (jj == 2) ? v03[2] : e;              \
  e = (jj == 3) ? v03[3] : e; e = (jj == 4) ? v47[0] : e;              \
  e = (jj == 5) ? v47[1] : e; e = (jj == 6) ? v47[2] : e;              \
  e = (jj == 7) ? v47[3] : e

// One full OMP solve for one signal; cr in 2 f32x4 refs. Q cols in registers
// for ortho (write-through); LDS keeps copies of cols 0-2 for the
// uniform-address w_u = Q_u[khat] broadcast extracts.
__device__ __forceinline__ float omp_one(
    f32x4& c03, f32x4& c47,
    float* __restrict__ QW,            // [3][512] float
    const float* __restrict__ G, const float* __restrict__ DT,
    float* __restrict__ coeffs,
    int n, int lane, float zv) {
  int omega = 0xFF;
  int I0 = 0, I1 = 0, I2 = 0, I3 = 0, I4 = 0;
  float L10 = 0, L20 = 0, L21 = 0;
  float L30 = 0, L31 = 0, L32 = 0;
  float L40 = 0, L41 = 0, L42 = 0, L43 = 0;
  float d1v = 1.f, d2v = 1.f, d3v = 1.f, d4v = 1.f;
  float y0v = 0, y1v = 0, y2v = 0, y3v = 0, y4v = 0;
  DECLV(Qa); DECLV(Qb); DECLV(Qc); DECLV(Qd);   // all 4 cols in regs

  f32x4* QW4 = reinterpret_cast<f32x4*>(QW);    // [3][2][64]

  #pragma unroll
  for (int it = 0; it < 5; ++it) {
    // ---- argmax of |cr|*omega: pure-DPP reduce, first-index tie-break ----
    unsigned ab0 = (omega & 1)        ? (__float_as_uint(c03[0]) & 0x7FFFFFFFu) : 0u;
    unsigned ab1 = ((omega >> 1) & 1) ? (__float_as_uint(c03[1]) & 0x7FFFFFFFu) : 0u;
    unsigned ab2 = ((omega >> 2) & 1) ? (__float_as_uint(c03[2]) & 0x7FFFFFFFu) : 0u;
    unsigned ab3 = ((omega >> 3) & 1) ? (__float_as_uint(c03[3]) & 0x7FFFFFFFu) : 0u;
    unsigned ab4 = ((omega >> 4) & 1) ? (__float_as_uint(c47[0]) & 0x7FFFFFFFu) : 0u;
    unsigned ab5 = ((omega >> 5) & 1) ? (__float_as_uint(c47[1]) & 0x7FFFFFFFu) : 0u;
    unsigned ab6 = ((omega >> 6) & 1) ? (__float_as_uint(c47[2]) & 0x7FFFFFFFu) : 0u;
    unsigned ab7 = ((omega >> 7) & 1) ? (__float_as_uint(c47[3]) & 0x7FFFFFFFu) : 0u;
    unsigned la = umaxu(umaxu(umaxu(ab0, ab1), umaxu(ab2, ab3)),
                        umaxu(umaxu(ab4, ab5), umaxu(ab6, ab7)));
    unsigned rmax = la;
    rmax = dppmax(rmax, 0xB1);    // quad xor1
    rmax = dppmax(rmax, 0x4E);    // quad xor2
    rmax = dppmax(rmax, 0x124);   // row_ror:4
    rmax = dppmax(rmax, 0x128);   // row_ror:8  -> per-row max
    rmax = dppmax(rmax, 0x142);   // row_bcast15
    rmax = dppmax(rmax, 0x143);   // row_bcast31 -> lane 63 has global max
    unsigned gmu = (unsigned)__builtin_amdgcn_readlane((int)rmax, 63);
    unsigned long long ball = __ballot(la == gmu);
    const int sl = __ffsll((long long)ball) - 1;   // lowest winning lane
    int jb = 7;
    jb = (ab6 == gmu) ? 6 : jb;
    jb = (ab5 == gmu) ? 5 : jb;
    jb = (ab4 == gmu) ? 4 : jb;
    jb = (ab3 == gmu) ? 3 : jb;
    jb = (ab2 == gmu) ? 2 : jb;
    jb = (ab1 == gmu) ? 1 : jb;
    jb = (ab0 == gmu) ? 0 : jb;
    const int jj = __builtin_amdgcn_readlane(jb, sl) & 7;
    const int khat = (sl << 3) | jj;
    if (lane == sl) omega &= ~(1 << jj);

    // ---- uniform-address LDS extractions of w_u = Q_u[khat] (issue early) --
    const int eoff = ((khat >> 2) & 1) * 256 + (khat >> 3) * 4 + (khat & 3);
    float w0 = 0.f, w1 = 0.f, w2 = 0.f, w3 = 0.f;
    if (it > 0) w0 = QW[eoff];
    if (it > 1) w1 = QW[512 + eoff];
    if (it > 2) w2 = QW[1024 + eoff];
    if (it > 3) { float e; SEL8V(e, Qd03, Qd47); w3 = bcastf(e, sl); }

    // new G row load (consumed after scalar chain)
    f32x4 na = {0, 0, 0, 0}, nbv = {0, 0, 0, 0};
    if (it < 4) {
      na  = *reinterpret_cast<const f32x4*>(G + khat * KAT + 8 * lane);
      nbv = *reinterpret_cast<const f32x4*>(G + khat * KAT + 8 * lane + 4);
    }

    // crv = cr[khat] (register select + broadcast, overlaps LDS latency)
    float crv;
    { float e; SEL8V(e, c03, c47); crv = bcastf(e, sl); }

    // ---- scalar chain: dn = rsqrt(1-||w||^2); y_it = crv*dn ----
    float s2 = 1.f - w0 * w0 - w1 * w1 - w2 * w2 - w3 * w3;
    float dn = __builtin_amdgcn_rsqf(s2);          // rsq(1.0)==1.0 at it==0
    float yn = crv * dn;
    if (it == 0) { I0 = khat; y0v = yn; }
    if (it == 1) { I1 = khat; y1v = yn; L10 = w0; d1v = dn; }
    if (it == 2) { I2 = khat; y2v = yn; L20 = w0; L21 = w1; d2v = dn; }
    if (it == 3) { I3 = khat; y3v = yn; L30 = w0; L31 = w1; L32 = w2; d3v = dn; }
    if (it == 4) { I4 = khat; y4v = yn; L40 = w0; L41 = w1; L42 = w2; L43 = w3; d4v = dn; }

    // ---- orthogonalize new column (packed FMA); rank-1 update ----
    if (it < 4) {
      f32x4 qn03 = na, qn47 = nbv;
      if (it > 0) {
        f32x4 w4 = splat4(-w0);
        qn03 = __builtin_elementwise_fma(w4, Qa03, qn03);
        qn47 = __builtin_elementwise_fma(w4, Qa47, qn47);
      }
      if (it > 1) {
        f32x4 w4 = splat4(-w1);
        qn03 = __builtin_elementwise_fma(w4, Qb03, qn03);
        qn47 = __builtin_elementwise_fma(w4, Qb47, qn47);
      }
      if (it > 2) {
        f32x4 w4 = splat4(-w2);
        qn03 = __builtin_elementwise_fma(w4, Qc03, qn03);
        qn47 = __builtin_elementwise_fma(w4, Qc47, qn47);
      }
      f32x4 dn4 = splat4(dn);
      qn03 = qn03 * dn4;
      qn47 = qn47 * dn4;
      if (it < 3) {   // LDS copy only for future uniform extracts
        QW4[it * 128 + lane]      = qn03;
        QW4[it * 128 + 64 + lane] = qn47;
      }
      if (it == 0) { Qa03 = qn03; Qa47 = qn47; }
      if (it == 1) { Qb03 = qn03; Qb47 = qn47; }
      if (it == 2) { Qc03 = qn03; Qc47 = qn47; }
      if (it == 3) { Qd03 = qn03; Qd47 = qn47; }
      f32x4 yn4 = splat4(-yn);
      c03 = __builtin_elementwise_fma(yn4, qn03, c03);
      c47 = __builtin_elementwise_fma(yn4, qn47, c47);
    }
  } // it

  // ---- back-substitution (once) + epilogue ----
  float x4 = y4v * d4v;
  float x3 = (y3v - L43 * x4) * d3v;
  float x2 = (y2v - L32 * x3 - L42 * x4) * d2v;
  float x1 = (y1v - L21 * x2 - L31 * x3 - L41 * x4) * d1v;
  float x0 =  y0v - L10 * x1 - L20 * x2 - L30 * x3 - L40 * x4;

  if (lane < 5) {
    int It = I0; float xt = x0;
    if (lane == 1) { It = I1; xt = x1; }
    if (lane == 2) { It = I2; xt = x2; }
    if (lane == 3) { It = I3; xt = x3; }
    if (lane == 4) { It = I4; xt = x4; }
    coeffs[(long)It * NSIG + n] = xt;
  }
  float rec = x0 * DT[I0 * 64 + lane];
  rec = fmaf(x1, DT[I1 * 64 + lane], rec);
  rec = fmaf(x2, DT[I2 * 64 + lane], rec);
  rec = fmaf(x3, DT[I3 * 64 + lane], rec);
  rec = fmaf(x4, DT[I4 * 64 + lane], rec);
  return rec - zv;                       // d = z_dl - z (per-lane component)
}

// one wave per block; 6 KB LDS for Q cols 0..2 extract copies
__global__ __launch_bounds__(64) void k_omp(
    const float* __restrict__ D, const float* __restrict__ G,
    const float* __restrict__ DT, const float* __restrict__ ST,
    float* __restrict__ out0, float* __restrict__ lossp,
    float* __restrict__ coeffs) {
  __shared__ float QL[3][512];
  const int lane = threadIdx.x;
  const int wid  = blockIdx.x;                              // 0..8191
  // strided signal mapping: n_j = cc + 512*w3 + 64*j (j=0..7): each lane's
  // 8 out0 values are consecutive floats -> coalesced stores, no write amp.
  const int cc = wid >> 7;          // 0..63  (= n & 63)
  const int w3 = wid & 127;
  const int nbase = cc + 512 * w3;
  const float* Dp = D + 8 * lane;
  float* QW = &QL[0][0];
  float lossacc = 0.f;

  // ONE group of 8 signals: D streamed from L2 exactly once per wave.
  const int n0 = nbase;             const int n1 = nbase + 64;
  const int n2 = nbase + 128;       const int n3 = nbase + 192;
  const int n4 = nbase + 256;       const int n5 = nbase + 320;
  const int n6 = nbase + 384;       const int n7 = nbase + 448;
  float svA = ST[n0 * 64 + lane];
  float svB = ST[n1 * 64 + lane];
  float svC = ST[n2 * 64 + lane];
  float svD = ST[n3 * 64 + lane];
  float svE = ST[n4 * 64 + lane];
  float svF = ST[n5 * 64 + lane];
  float svG = ST[n6 * 64 + lane];
  float svH = ST[n7 * 64 + lane];

  DECLV(cA); DECLV(cB); DECLV(cC); DECLV(cD);
  DECLV(cE); DECLV(cF); DECLV(cG); DECLV(cH);

  #pragma unroll 2
  for (int r = 0; r < 64; ++r) {
    const f32x4 d03 = *reinterpret_cast<const f32x4*>(Dp + r * KAT);
    const f32x4 d47 = *reinterpret_cast<const f32x4*>(Dp + r * KAT + 4);
    const float sA = bcastf(svA, r);
    const float sB = bcastf(svB, r);
    const float sC = bcastf(svC, r);
    const float sD = bcastf(svD, r);
    const float sE = bcastf(svE, r);
    const float sF = bcastf(svF, r);
    const float sG = bcastf(svG, r);
    const float sH = bcastf(svH, r);
    FMA8V(cA, sA) FMA8V(cB, sB) FMA8V(cC, sC) FMA8V(cD, sD)
    FMA8V(cE, sE) FMA8V(cF, sF) FMA8V(cG, sG) FMA8V(cH, sH)
  }

  float dA = omp_one(cA03, cA47, QW, G, DT, coeffs, n0, lane, svA);
  lossacc = fmaf(dA, dA, lossacc);
  float dB = omp_one(cB03, cB47, QW, G, DT, coeffs, n1, lane, svB);
  lossacc = fmaf(dB, dB, lossacc);
  float dC = omp_one(cC03, cC47, QW, G, DT, coeffs, n2, lane, svC);
  lossacc = fmaf(dC, dC, lossacc);
  float dD = omp_one(cD03, cD47, QW, G, DT, coeffs, n3, lane, svD);
  lossacc = fmaf(dD, dD, lossacc);
  float dE = omp_one(cE03, cE47, QW, G, DT, coeffs, n4, lane, svE);
  lossacc = fmaf(dE, dE, lossacc);
  float dF = omp_one(cF03, cF47, QW, G, DT, coeffs, n5, lane, svF);
  lossacc = fmaf(dF, dF, lossacc);
  float dG = omp_one(cG03, cG47, QW, G, DT, coeffs, n6, lane, svG);
  lossacc = fmaf(dG, dG, lossacc);
  float dH = omp_one(cH03, cH47, QW, G, DT, coeffs, n7, lane, svH);
  lossacc = fmaf(dH, dH, lossacc);

  // out0: 8 consecutive floats per lane (32B-aligned), two dwordx4 stores
  const int obase = lane * 65536 + cc * 1024 + (w3 >> 2) * 32 + (w3 & 3) * 8;
  *reinterpret_cast<float4*>(out0 + obase) =
      make_float4(svA + dA, svB + dB, svC + dC, svD + dD);
  *reinterpret_cast<float4*>(out0 + obase + 4) =
      make_float4(svE + dE, svF + dF, svG + dG, svH + dH);

  #pragma unroll
  for (int off = 32; off > 0; off >>= 1) lossacc += __shfl_xor(lossacc, off);
  if (lane == 0) atomicAdd(lossp, lossacc * (1.25f / 4194304.f));
}

extern "C" void kernel_launch(void* const* d_in, const int* in_sizes, int n_in,
                              void* d_out, int out_size, void* d_ws, size_t ws_size,
                              hipStream_t stream) {
  const float* ze = (const float*)d_in[0];
  const float* D  = (const float*)d_in[1];
  float* out0 = (float*)d_out;
  float* lossp = out0 + 4194304;
  float* coeffs = out0 + 4194305;

  float* wsf = (float*)d_ws;
  float* G  = wsf;              // 262144 floats
  float* DT = wsf + 262144;     // 32768 floats
  float* ST = wsf + 294912;     // 4194304 floats

  // zero loss + coeffs (out0 is fully overwritten)
  (void)hipMemsetAsync((char*)d_out + 16777216ull, 0, 134217732ull, stream);

  hipLaunchKernelGGL(k_gram, dim3(1024), dim3(256), 0, stream, D, G, DT);
  hipLaunchKernelGGL(k_tr,   dim3(2048), dim3(256), 0, stream, ze, ST);
  hipLaunchKernelGGL(k_omp,  dim3(8192), dim3(64), 0, stream,
                     D, G, DT, ST, out0, lossp, coeffs);
}